// Round 9
// baseline (928.726 us; speedup 1.0000x reference)
//
#include <hip/hip_runtime.h>
#include <hip/hip_cooperative_groups.h>
#include <hip/hip_fp16.h>
#include <math.h>

namespace cg = cooperative_groups;

// ---------------------------------------------------------------------------
// 2-layer GAT on MI355X (gfx950) — R9: single cooperative mega-kernel.
// Phases (grid.sync between): A zero-deg + W1/W2 transpose->fp16 | B degree
// hist | C per-chunk sums | D exclusive scan -> rowptr/cursor | E1 gemm1
// (MFMA 16x16x32_f16, fused att coefficients) | E2 scatter -> csr_src |
// F agg1 (single-pass softmax, +bias+ELU, fp16 out) | G gemm2 (MFMA, fused
// att) | H agg2 (+bias). All phases grid-stride over a co-resident grid.
// Removes 8 dispatch boundaries vs R8 (est. ~100us of gaps).
// ---------------------------------------------------------------------------

#define LEAKY(e) ((e) > 0.f ? (e) : 0.2f * (e))

struct __align__(8) H4 { __half2 a, b; };  // 4 halves

typedef _Float16 half8 __attribute__((ext_vector_type(8)));
typedef float f32x4 __attribute__((ext_vector_type(4)));

struct Params {
  const float* x;
  const int* ei;
  const float* W1;
  const float* W2;
  const float* att_src1;
  const float* att_dst1;
  const float* bias1;
  const float* att_src2;
  const float* att_dst2;
  const float* bias2;
  float* out;
  _Float16* Bt1;
  _Float16* Bt2;
  _Float16* h1h;
  _Float16* h2h;
  _Float16* h_act;
  float* a_src1;
  float* a_dst1;
  float* a_src2;
  float* a_dst2;
  int* rowptr;
  int* cursor;
  int* deg;
  int* bsum;
  int* csr_src;
  int N;
  int E;
};

// ------- MFMA GEMM tile + fused attention coefficients (device fn) ---------
// C[n,NTOT] = A[n,K] @ B[K,NTOT]; A row-major (fp32 if AF32 else fp16),
// Bt fp16 [NTOT][K]. Tile: 128x64 per 4-wave block unit; wave tile 32x64.
template <int K, int NTOT, bool AF32>
__device__ __forceinline__ void gemm_tile(
    const void* __restrict__ Av, const _Float16* __restrict__ Bt,
    _Float16* __restrict__ Ch, const float* __restrict__ att_src,
    const float* __restrict__ att_dst, float* __restrict__ a_src,
    float* __restrict__ a_dst, int n, int bx, int by, int w, int l) {
  int lm = l & 15, lq = l >> 4;
  int m0 = bx * 128 + w * 32;
  int c0 = by * 64;
  int ra = m0 + lm;      if (ra > n - 1) ra = n - 1;
  int rb = m0 + 16 + lm; if (rb > n - 1) rb = n - 1;
  f32x4 acc[2][4];
#pragma unroll
  for (int mt = 0; mt < 2; mt++)
#pragma unroll
    for (int nt = 0; nt < 4; nt++) acc[mt][nt] = (f32x4){0.f, 0.f, 0.f, 0.f};
  for (int k0 = 0; k0 < K; k0 += 32) {
    half8 a0, a1;
    if (AF32) {
      const float* pa = (const float*)Av + (size_t)ra * K + k0 + lq * 8;
      const float* pb = (const float*)Av + (size_t)rb * K + k0 + lq * 8;
      float4 u0 = *(const float4*)pa, u1 = *(const float4*)(pa + 4);
      float4 w0 = *(const float4*)pb, w1 = *(const float4*)(pb + 4);
      a0[0] = (_Float16)u0.x; a0[1] = (_Float16)u0.y;
      a0[2] = (_Float16)u0.z; a0[3] = (_Float16)u0.w;
      a0[4] = (_Float16)u1.x; a0[5] = (_Float16)u1.y;
      a0[6] = (_Float16)u1.z; a0[7] = (_Float16)u1.w;
      a1[0] = (_Float16)w0.x; a1[1] = (_Float16)w0.y;
      a1[2] = (_Float16)w0.z; a1[3] = (_Float16)w0.w;
      a1[4] = (_Float16)w1.x; a1[5] = (_Float16)w1.y;
      a1[6] = (_Float16)w1.z; a1[7] = (_Float16)w1.w;
    } else {
      a0 = *(const half8*)((const _Float16*)Av + (size_t)ra * K + k0 + lq * 8);
      a1 = *(const half8*)((const _Float16*)Av + (size_t)rb * K + k0 + lq * 8);
    }
    half8 b0 = *(const half8*)(Bt + (size_t)(c0 + 0 + lm) * K + k0 + lq * 8);
    half8 b1 = *(const half8*)(Bt + (size_t)(c0 + 16 + lm) * K + k0 + lq * 8);
    half8 b2 = *(const half8*)(Bt + (size_t)(c0 + 32 + lm) * K + k0 + lq * 8);
    half8 b3 = *(const half8*)(Bt + (size_t)(c0 + 48 + lm) * K + k0 + lq * 8);
    acc[0][0] = __builtin_amdgcn_mfma_f32_16x16x32_f16(a0, b0, acc[0][0], 0, 0, 0);
    acc[0][1] = __builtin_amdgcn_mfma_f32_16x16x32_f16(a0, b1, acc[0][1], 0, 0, 0);
    acc[0][2] = __builtin_amdgcn_mfma_f32_16x16x32_f16(a0, b2, acc[0][2], 0, 0, 0);
    acc[0][3] = __builtin_amdgcn_mfma_f32_16x16x32_f16(a0, b3, acc[0][3], 0, 0, 0);
    acc[1][0] = __builtin_amdgcn_mfma_f32_16x16x32_f16(a1, b0, acc[1][0], 0, 0, 0);
    acc[1][1] = __builtin_amdgcn_mfma_f32_16x16x32_f16(a1, b1, acc[1][1], 0, 0, 0);
    acc[1][2] = __builtin_amdgcn_mfma_f32_16x16x32_f16(a1, b2, acc[1][2], 0, 0, 0);
    acc[1][3] = __builtin_amdgcn_mfma_f32_16x16x32_f16(a1, b3, acc[1][3], 0, 0, 0);
  }
  float as_[4], ad_[4];
#pragma unroll
  for (int nt = 0; nt < 4; nt++) {
    as_[nt] = att_src[c0 + nt * 16 + lm];
    ad_[nt] = att_dst[c0 + nt * 16 + lm];
  }
#pragma unroll
  for (int mt = 0; mt < 2; mt++) {
#pragma unroll
    for (int i = 0; i < 4; i++) {
      int gr = m0 + mt * 16 + lq * 4 + i;
      bool ok = gr < n;
      if (ok) {
#pragma unroll
        for (int nt = 0; nt < 4; nt++)
          Ch[(size_t)gr * NTOT + c0 + nt * 16 + lm] = (_Float16)acc[mt][nt][i];
      }
      float p0 = acc[mt][0][i] * as_[0] + acc[mt][1][i] * as_[1];
      float p1 = acc[mt][2][i] * as_[2] + acc[mt][3][i] * as_[3];
      float q0 = acc[mt][0][i] * ad_[0] + acc[mt][1][i] * ad_[1];
      float q1 = acc[mt][2][i] * ad_[2] + acc[mt][3][i] * ad_[3];
#pragma unroll
      for (int o = 1; o < 16; o <<= 1) {
        p0 += __shfl_xor(p0, o, 64);
        p1 += __shfl_xor(p1, o, 64);
        q0 += __shfl_xor(q0, o, 64);
        q1 += __shfl_xor(q1, o, 64);
      }
      if (lm == 0 && ok) {
        if (NTOT == 256) {
          int h0 = c0 >> 5;
          a_src[(size_t)gr * 8 + h0] = p0;
          a_src[(size_t)gr * 8 + h0 + 1] = p1;
          a_dst[(size_t)gr * 8 + h0] = q0;
          a_dst[(size_t)gr * 8 + h0 + 1] = q1;
        } else {
          a_src[gr] = p0 + p1;
          a_dst[gr] = q0 + q1;
        }
      }
    }
  }
}

// ----------------------------- mega kernel ---------------------------------
__global__ __launch_bounds__(256, 4) void mega_kernel(Params P) {
  cg::grid_group grid = cg::this_grid();
  __shared__ int sb[256];
  __shared__ int ws[4];
  int t = threadIdx.x;
  int b = blockIdx.x;
  int GB = gridDim.x;
  int NT = GB * 256;
  int tid = b * 256 + t;
  int w = t >> 6, l = t & 63;
  int N = P.N, E = P.E, Etot = E + N;
  int nb = (N + 255) >> 8;

  // ---- Phase A: zero deg + W transposes (all fit in one grid pass) ----
  if (tid < N) P.deg[tid] = 0;
  if (tid < 256 * 128) {
    int nn = tid >> 7, kk = tid & 127;
    P.Bt1[tid] = (_Float16)P.W1[kk * 256 + nn];
  }
  if (tid < 64 * 256) {
    int nn = tid >> 8, kk = tid & 255;
    P.Bt2[tid] = (_Float16)P.W2[kk * 64 + nn];
  }
  grid.sync();

  // ---- Phase B: degree histogram ----
  for (int i = tid; i < Etot; i += NT) {
    int d = (i < E) ? P.ei[E + i] : (i - E);
    atomicAdd(&P.deg[d], 1);
  }
  grid.sync();

  // ---- Phase C: per-256-chunk sums ----
  if (b < nb) {
    int i = b * 256 + t;
    int v = (i < N) ? P.deg[i] : 0;
    int wv = v;
#pragma unroll
    for (int o = 32; o; o >>= 1) wv += __shfl_xor(wv, o, 64);
    if ((t & 63) == 0) ws[t >> 6] = wv;
    __syncthreads();
    if (t == 0) P.bsum[b] = ws[0] + ws[1] + ws[2] + ws[3];
  }
  grid.sync();

  // ---- Phase D: exclusive scan -> rowptr, cursor (nb <= 256) ----
  if (b < nb) {
    int vb = (t < b) ? P.bsum[t] : 0;
    int wv = vb;
#pragma unroll
    for (int o = 32; o; o >>= 1) wv += __shfl_xor(wv, o, 64);
    if ((t & 63) == 0) ws[t >> 6] = wv;
    __syncthreads();
    int carry = ws[0] + ws[1] + ws[2] + ws[3];
    int i = b * 256 + t;
    int v = (i < N) ? P.deg[i] : 0;
    sb[t] = v;
    __syncthreads();
    int x = v;
    for (int off = 1; off < 256; off <<= 1) {
      int y = (t >= off) ? sb[t - off] : 0;
      __syncthreads();
      x += y;
      sb[t] = x;
      __syncthreads();
    }
    int excl = x - v + carry;
    if (i < N) {
      P.rowptr[i] = excl;
      P.cursor[i] = excl;
    }
    if (i == N - 1) P.rowptr[N] = excl + v;
  }
  grid.sync();

  // ---- Phase E1: gemm1 (x fp32 -> fp16 in-register), fused att coeffs ----
  {
    int tiles = ((N + 127) >> 7) * 4;
    for (int tile = b; tile < tiles; tile += GB)
      gemm_tile<128, 256, true>(P.x, P.Bt1, P.h1h, P.att_src1, P.att_dst1,
                                P.a_src1, P.a_dst1, N, tile >> 2, tile & 3, w, l);
  }
  grid.sync();

  // ---- Phase E2: scatter -> csr_src ----
  for (int i = tid; i < Etot; i += NT) {
    int s, d;
    if (i < E) {
      s = P.ei[i];
      d = P.ei[E + i];
    } else {
      s = d = i - E;
    }
    int pos = atomicAdd(&P.cursor[d], 1);
    P.csr_src[pos] = s;
  }
  grid.sync();

  // ---- Phase F: agg1 — wave per dst, single-pass softmax, bias+ELU ----
  {
    int groups = (N + 3) >> 2;
    for (int g = b; g < groups; g += GB) {
      int d = g * 4 + w;
      if (d >= N) continue;
      int base = P.rowptr[d], cnt = P.rowptr[d + 1] - base;
      const int* sp = P.csr_src + base;
      int hh = l >> 3;
      float adst = P.a_dst1[(size_t)d * 8 + hh];
      float4 acc = make_float4(0.f, 0.f, 0.f, 0.f);
      float p = 0.f;
      int i = 0;
      for (; i + 8 <= cnt; i += 8) {
        int s[8];
        H4 v[8];
        float xv[8];
#pragma unroll
        for (int j = 0; j < 8; j++) s[j] = sp[i + j];
#pragma unroll
        for (int j = 0; j < 8; j++)
          v[j] = *(const H4*)((const __half*)P.h1h + (size_t)s[j] * 256 + 4 * l);
#pragma unroll
        for (int j = 0; j < 8; j++) {
          float e = P.a_src1[(size_t)s[j] * 8 + hh] + adst;
          e = LEAKY(e);
          xv[j] = __expf(e);
          p += xv[j];
        }
#pragma unroll
        for (int j = 0; j < 8; j++) {
          float2 p0 = __half22float2(v[j].a), p1 = __half22float2(v[j].b);
          acc.x = fmaf(p0.x, xv[j], acc.x);
          acc.y = fmaf(p0.y, xv[j], acc.y);
          acc.z = fmaf(p1.x, xv[j], acc.z);
          acc.w = fmaf(p1.y, xv[j], acc.w);
        }
      }
      for (; i < cnt; i++) {
        int s = sp[i];
        float e = P.a_src1[(size_t)s * 8 + hh] + adst;
        e = LEAKY(e);
        float a = __expf(e);
        p += a;
        H4 v = *(const H4*)((const __half*)P.h1h + (size_t)s * 256 + 4 * l);
        float2 p0 = __half22float2(v.a), p1 = __half22float2(v.b);
        acc.x = fmaf(p0.x, a, acc.x);
        acc.y = fmaf(p0.y, a, acc.y);
        acc.z = fmaf(p1.x, a, acc.z);
        acc.w = fmaf(p1.y, a, acc.w);
      }
      float rinv = 1.f / (p + 1e-16f);
      float4 bb = *(const float4*)(P.bias1 + 4 * l);
      float ox = fmaf(acc.x, rinv, bb.x), oy = fmaf(acc.y, rinv, bb.y);
      float oz = fmaf(acc.z, rinv, bb.z), ow = fmaf(acc.w, rinv, bb.w);
      ox = ox > 0.f ? ox : expm1f(ox);
      oy = oy > 0.f ? oy : expm1f(oy);
      oz = oz > 0.f ? oz : expm1f(oz);
      ow = ow > 0.f ? ow : expm1f(ow);
      H4 hv;
      hv.a = __floats2half2_rn(ox, oy);
      hv.b = __floats2half2_rn(oz, ow);
      *(H4*)(P.h_act + (size_t)d * 256 + 4 * l) = hv;
    }
  }
  grid.sync();

  // ---- Phase G: gemm2 (fp16 A), fused att coeffs ----
  {
    int tiles = (N + 127) >> 7;
    for (int tile = b; tile < tiles; tile += GB)
      gemm_tile<256, 64, false>(P.h_act, P.Bt2, P.h2h, P.att_src2, P.att_dst2,
                                P.a_src2, P.a_dst2, N, tile, 0, w, l);
  }
  grid.sync();

  // ---- Phase H: agg2 — wave per dst, single-pass softmax, bias ----
  {
    int groups = (N + 3) >> 2;
    for (int g = b; g < groups; g += GB) {
      int d = g * 4 + w;
      if (d >= N) continue;
      int base = P.rowptr[d], cnt = P.rowptr[d + 1] - base;
      const int* sp = P.csr_src + base;
      float adst = P.a_dst2[d];
      int e2 = l >> 5;
      int c2 = (l & 31) * 2;
      float2 acc = make_float2(0.f, 0.f);
      float p = 0.f;
      int i = 0;
      for (; i + 16 <= cnt; i += 16) {
        int s[8];
        __half2 v[8];
        float xv[8];
#pragma unroll
        for (int j = 0; j < 8; j++) s[j] = sp[i + j * 2 + e2];
#pragma unroll
        for (int j = 0; j < 8; j++)
          v[j] = *(const __half2*)((const __half*)P.h2h + (size_t)s[j] * 64 + c2);
#pragma unroll
        for (int j = 0; j < 8; j++) {
          float e = P.a_src2[s[j]] + adst;
          e = LEAKY(e);
          xv[j] = __expf(e);
          p += xv[j];
        }
#pragma unroll
        for (int j = 0; j < 8; j++) {
          float2 f = __half22float2(v[j]);
          acc.x = fmaf(f.x, xv[j], acc.x);
          acc.y = fmaf(f.y, xv[j], acc.y);
        }
      }
      for (; i + e2 < cnt; i += 2) {
        int s = sp[i + e2];
        float e = P.a_src2[s] + adst;
        e = LEAKY(e);
        float a = __expf(e);
        p += a;
        float2 f = __half22float2(
            *(const __half2*)((const __half*)P.h2h + (size_t)s * 64 + c2));
        acc.x = fmaf(f.x, a, acc.x);
        acc.y = fmaf(f.y, a, acc.y);
      }
      acc.x += __shfl_xor(acc.x, 32, 64);
      acc.y += __shfl_xor(acc.y, 32, 64);
      p += __shfl_xor(p, 32, 64);
      if (l < 32) {
        float rinv = 1.f / (p + 1e-16f);
        float2 bb = *(const float2*)(P.bias2 + c2);
        *(float2*)(P.out + (size_t)d * 64 + c2) =
            make_float2(fmaf(acc.x, rinv, bb.x), fmaf(acc.y, rinv, bb.y));
      }
    }
  }
}

// ---------------------------------------------------------------------------
extern "C" void kernel_launch(void* const* d_in, const int* in_sizes, int n_in,
                              void* d_out, int out_size, void* d_ws, size_t ws_size,
                              hipStream_t stream) {
  int N = in_sizes[0] / 128;
  int E = in_sizes[1] / 2;
  int Etot = E + N;
  int nb = (N + 255) / 256;

  char* ws = (char*)d_ws;
  size_t off = 0;
  auto carve = [&](size_t bytes) -> void* {
    void* p = ws + off;
    off += (bytes + 255) & ~(size_t)255;
    return p;
  };
  Params P;
  P.x        = (const float*)d_in[0];
  P.ei       = (const int*)d_in[1];
  P.W1       = (const float*)d_in[3];
  P.att_src1 = (const float*)d_in[4];
  P.att_dst1 = (const float*)d_in[5];
  P.bias1    = (const float*)d_in[6];
  P.W2       = (const float*)d_in[7];
  P.att_src2 = (const float*)d_in[8];
  P.att_dst2 = (const float*)d_in[9];
  P.bias2    = (const float*)d_in[10];
  P.out      = (float*)d_out;
  P.Bt1    = (_Float16*)carve((size_t)256 * 128 * 2);
  P.Bt2    = (_Float16*)carve((size_t)64 * 256 * 2);
  P.h1h    = (_Float16*)carve((size_t)N * 256 * 2);
  P.h2h    = (_Float16*)carve((size_t)N * 64 * 2);
  P.h_act  = (_Float16*)carve((size_t)N * 256 * 2);
  P.a_src1 = (float*)carve((size_t)N * 8 * 4);
  P.a_dst1 = (float*)carve((size_t)N * 8 * 4);
  P.a_src2 = (float*)carve((size_t)N * 4);
  P.a_dst2 = (float*)carve((size_t)N * 4);
  P.rowptr = (int*)carve((size_t)(N + 1) * 4);
  P.cursor = (int*)carve((size_t)N * 4);
  P.deg    = (int*)carve((size_t)N * 4);
  P.bsum   = (int*)carve((size_t)nb * 4);
  P.csr_src= (int*)carve((size_t)Etot * 4);
  P.N = N;
  P.E = E;
  (void)ws_size; (void)n_in; (void)out_size;

  int maxb = 0;
  hipOccupancyMaxActiveBlocksPerMultiprocessor(&maxb, mega_kernel, 256, 0);
  if (maxb < 1) maxb = 1;
  long long grid = (long long)maxb * 256;  // 256 CUs on MI355X
  if (grid > 2048) grid = 2048;
  if (grid < 256) grid = 256;  // scan phases need >= nb (196) blocks
  void* args[] = {&P};
  hipLaunchCooperativeKernel((void*)mega_kernel, dim3((int)grid), dim3(256),
                             args, 0, stream);
}

// Round 10
// 430.353 us; speedup vs baseline: 2.1581x; 2.1581x over previous
//
#include <hip/hip_runtime.h>
#include <hip/hip_fp16.h>
#include <math.h>

// ---------------------------------------------------------------------------
// 2-layer GAT on MI355X (gfx950).
// L1: in=128, H=8, C=32 (concat->256) +bias1, ELU.  L2: in=256, H=1, C=64 +bias2.
// R10: revert coop mega-kernel (grid.sync ~100us/sync on MI355X — measured
// R9). Back to R8 multi-dispatch, plus: (a) head-major gather tables
// h1p[8][N][32] / h2p[2][N][32] fp16 with XCD-affine (blockIdx&7 / &1)
// aggregation waves = R4's measured FETCH collapse (205->46MB), but with
// 8-slot x 8-lane x 8B gathers + single-pass softmax so the per-lane
// instruction stream equals R8's (R4's 2x bloat fixed); (b) independent-phase
// merges: prep||hist, gemm1||scan1. 1 memset + 7 kernels.
// ---------------------------------------------------------------------------

#define LEAKY(e) ((e) > 0.f ? (e) : 0.2f * (e))

struct __align__(8) H4 { __half2 a, b; };  // 4 halves

typedef _Float16 half8 __attribute__((ext_vector_type(8)));
typedef float f32x4 __attribute__((ext_vector_type(4)));

// ------- MFMA GEMM tile + fused attention coefficients (device fn) ---------
// C = A[n,K] @ B[K,NTOT]; A row-major (fp32 if AF32 else fp16), Bt fp16
// [NTOT][K]. Output Chp is SLICE-MAJOR: [NTOT/32][n][32]. a_src/a_dst:
// NTOT=256 -> head-major [8][n]; NTOT=64 -> flat [n].
template <int K, int NTOT, bool AF32>
__device__ __forceinline__ void gemm_tile(
    const void* __restrict__ Av, const _Float16* __restrict__ Bt,
    _Float16* __restrict__ Chp, const float* __restrict__ att_src,
    const float* __restrict__ att_dst, float* __restrict__ a_src,
    float* __restrict__ a_dst, int n, int bx, int by, int w, int l) {
  int lm = l & 15, lq = l >> 4;
  int m0 = bx * 128 + w * 32;
  int c0 = by * 64;
  int ra = m0 + lm;      if (ra > n - 1) ra = n - 1;
  int rb = m0 + 16 + lm; if (rb > n - 1) rb = n - 1;
  f32x4 acc[2][4];
#pragma unroll
  for (int mt = 0; mt < 2; mt++)
#pragma unroll
    for (int nt = 0; nt < 4; nt++) acc[mt][nt] = (f32x4){0.f, 0.f, 0.f, 0.f};
  for (int k0 = 0; k0 < K; k0 += 32) {
    half8 a0, a1;
    if (AF32) {
      const float* pa = (const float*)Av + (size_t)ra * K + k0 + lq * 8;
      const float* pb = (const float*)Av + (size_t)rb * K + k0 + lq * 8;
      float4 u0 = *(const float4*)pa, u1 = *(const float4*)(pa + 4);
      float4 w0 = *(const float4*)pb, w1 = *(const float4*)(pb + 4);
      a0[0] = (_Float16)u0.x; a0[1] = (_Float16)u0.y;
      a0[2] = (_Float16)u0.z; a0[3] = (_Float16)u0.w;
      a0[4] = (_Float16)u1.x; a0[5] = (_Float16)u1.y;
      a0[6] = (_Float16)u1.z; a0[7] = (_Float16)u1.w;
      a1[0] = (_Float16)w0.x; a1[1] = (_Float16)w0.y;
      a1[2] = (_Float16)w0.z; a1[3] = (_Float16)w0.w;
      a1[4] = (_Float16)w1.x; a1[5] = (_Float16)w1.y;
      a1[6] = (_Float16)w1.z; a1[7] = (_Float16)w1.w;
    } else {
      a0 = *(const half8*)((const _Float16*)Av + (size_t)ra * K + k0 + lq * 8);
      a1 = *(const half8*)((const _Float16*)Av + (size_t)rb * K + k0 + lq * 8);
    }
    half8 b0 = *(const half8*)(Bt + (size_t)(c0 + 0 + lm) * K + k0 + lq * 8);
    half8 b1 = *(const half8*)(Bt + (size_t)(c0 + 16 + lm) * K + k0 + lq * 8);
    half8 b2 = *(const half8*)(Bt + (size_t)(c0 + 32 + lm) * K + k0 + lq * 8);
    half8 b3 = *(const half8*)(Bt + (size_t)(c0 + 48 + lm) * K + k0 + lq * 8);
    acc[0][0] = __builtin_amdgcn_mfma_f32_16x16x32_f16(a0, b0, acc[0][0], 0, 0, 0);
    acc[0][1] = __builtin_amdgcn_mfma_f32_16x16x32_f16(a0, b1, acc[0][1], 0, 0, 0);
    acc[0][2] = __builtin_amdgcn_mfma_f32_16x16x32_f16(a0, b2, acc[0][2], 0, 0, 0);
    acc[0][3] = __builtin_amdgcn_mfma_f32_16x16x32_f16(a0, b3, acc[0][3], 0, 0, 0);
    acc[1][0] = __builtin_amdgcn_mfma_f32_16x16x32_f16(a1, b0, acc[1][0], 0, 0, 0);
    acc[1][1] = __builtin_amdgcn_mfma_f32_16x16x32_f16(a1, b1, acc[1][1], 0, 0, 0);
    acc[1][2] = __builtin_amdgcn_mfma_f32_16x16x32_f16(a1, b2, acc[1][2], 0, 0, 0);
    acc[1][3] = __builtin_amdgcn_mfma_f32_16x16x32_f16(a1, b3, acc[1][3], 0, 0, 0);
  }
  float as_[4], ad_[4];
#pragma unroll
  for (int nt = 0; nt < 4; nt++) {
    as_[nt] = att_src[c0 + nt * 16 + lm];
    ad_[nt] = att_dst[c0 + nt * 16 + lm];
  }
#pragma unroll
  for (int mt = 0; mt < 2; mt++) {
#pragma unroll
    for (int i = 0; i < 4; i++) {
      int gr = m0 + mt * 16 + lq * 4 + i;
      bool ok = gr < n;
      if (ok) {
#pragma unroll
        for (int nt = 0; nt < 4; nt++) {
          int c = c0 + nt * 16 + lm;
          Chp[((size_t)(c >> 5) * n + gr) * 32 + (c & 31)] =
              (_Float16)acc[mt][nt][i];
        }
      }
      float p0 = acc[mt][0][i] * as_[0] + acc[mt][1][i] * as_[1];
      float p1 = acc[mt][2][i] * as_[2] + acc[mt][3][i] * as_[3];
      float q0 = acc[mt][0][i] * ad_[0] + acc[mt][1][i] * ad_[1];
      float q1 = acc[mt][2][i] * ad_[2] + acc[mt][3][i] * ad_[3];
#pragma unroll
      for (int o = 1; o < 16; o <<= 1) {
        p0 += __shfl_xor(p0, o, 64);
        p1 += __shfl_xor(p1, o, 64);
        q0 += __shfl_xor(q0, o, 64);
        q1 += __shfl_xor(q1, o, 64);
      }
      if (lm == 0 && ok) {
        if (NTOT == 256) {
          int h0 = c0 >> 5;  // heads h0, h0+1
          a_src[(size_t)h0 * n + gr] = p0;
          a_src[(size_t)(h0 + 1) * n + gr] = p1;
          a_dst[(size_t)h0 * n + gr] = q0;
          a_dst[(size_t)(h0 + 1) * n + gr] = q1;
        } else {
          a_src[gr] = p0 + p1;
          a_dst[gr] = q0 + q1;
        }
      }
    }
  }
}

// ------- K1: W transposes || degree histogram (independent families) -------
__global__ __launch_bounds__(256) void prep_hist_kernel(
    const float* __restrict__ W1, const float* __restrict__ W2,
    const int* __restrict__ ei, _Float16* __restrict__ Bt1,
    _Float16* __restrict__ Bt2, int* __restrict__ deg, int N, int E) {
  int t = threadIdx.x, b = blockIdx.x;
  if (b < 128) {
    int o = b * 256 + t;  // o = n*128 + k
    int nn = o >> 7, kk = o & 127;
    Bt1[o] = (_Float16)W1[kk * 256 + nn];
  } else if (b < 192) {
    int o = (b - 128) * 256 + t;  // o = n*256 + k
    int nn = o >> 8, kk = o & 255;
    Bt2[o] = (_Float16)W2[kk * 64 + nn];
  } else {
    int idx = (b - 192) * 256 + t;
    if (idx < E + N) {
      int d = (idx < E) ? ei[E + idx] : (idx - E);
      atomicAdd(&deg[d], 1);
    }
  }
}

// ------- K2: gemm1 tiles || scan1 chunk sums (independent families) --------
__global__ __launch_bounds__(256) void gemm1_scan1_kernel(
    const float* __restrict__ x, const _Float16* __restrict__ Bt1,
    _Float16* __restrict__ h1p, const float* __restrict__ att_src1,
    const float* __restrict__ att_dst1, float* __restrict__ a_src1h,
    float* __restrict__ a_dst1h, const int* __restrict__ deg,
    int* __restrict__ bsum, int N, int tiles1) {
  int b = blockIdx.x, t = threadIdx.x;
  if (b < tiles1) {
    gemm_tile<128, 256, true>(x, Bt1, h1p, att_src1, att_dst1, a_src1h,
                              a_dst1h, N, b >> 2, b & 3, t >> 6, t & 63);
  } else {
    __shared__ int ws[4];
    int bb = b - tiles1;
    int i = bb * 256 + t;
    int v = (i < N) ? deg[i] : 0;
    int wv = v;
#pragma unroll
    for (int o = 32; o; o >>= 1) wv += __shfl_xor(wv, o, 64);
    if ((t & 63) == 0) ws[t >> 6] = wv;
    __syncthreads();
    if (t == 0) bsum[bb] = ws[0] + ws[1] + ws[2] + ws[3];
  }
}

// ------- K3: exclusive scan -> rowptr, cursor (gridDim <= 256) -------------
__global__ __launch_bounds__(256) void scan3_kernel(
    const int* __restrict__ deg, const int* __restrict__ bsum,
    int* __restrict__ rowptr, int* __restrict__ cursor, int n) {
  __shared__ int sb[256];
  __shared__ int ws[4];
  int t = threadIdx.x;
  int vb = (t < (int)blockIdx.x) ? bsum[t] : 0;
  int wv = vb;
#pragma unroll
  for (int o = 32; o; o >>= 1) wv += __shfl_xor(wv, o, 64);
  if ((t & 63) == 0) ws[t >> 6] = wv;
  __syncthreads();
  int carry = ws[0] + ws[1] + ws[2] + ws[3];
  int i = blockIdx.x * 256 + t;
  int v = (i < n) ? deg[i] : 0;
  sb[t] = v;
  __syncthreads();
  int x = v;
  for (int off = 1; off < 256; off <<= 1) {
    int y = (t >= off) ? sb[t - off] : 0;
    __syncthreads();
    x += y;
    sb[t] = x;
    __syncthreads();
  }
  int excl = x - v + carry;
  if (i < n) {
    rowptr[i] = excl;
    cursor[i] = excl;
  }
  if (i == n - 1) rowptr[n] = excl + v;
}

// ------- K4: scatter -> csr_src --------------------------------------------
__global__ __launch_bounds__(256) void scatter_kernel(
    const int* __restrict__ ei, int E, int n, int* __restrict__ cursor,
    int* __restrict__ csr_src) {
  int idx = blockIdx.x * 256 + threadIdx.x;
  if (idx >= E + n) return;
  int s, d;
  if (idx < E) {
    s = ei[idx];
    d = ei[E + idx];
  } else {
    s = d = idx - E;
  }
  int pos = atomicAdd(&cursor[d], 1);
  csr_src[pos] = s;
}

// ------- K5: agg1 — wave = (dst, head), XCD-affine head (blockIdx&7) -------
// 8 edge-slots x 8 lanes x half4(8B). Single-pass softmax; slot-reduce at end.
__global__ __launch_bounds__(256) void agg1_kernel(
    const int* __restrict__ rowptr, const int* __restrict__ csr_src,
    const float* __restrict__ a_src1h, const float* __restrict__ a_dst1h,
    const __half* __restrict__ h1p, const float* __restrict__ bias,
    _Float16* __restrict__ h_act, int N) {
  int b = blockIdx.x;
  int head = b & 7, g = b >> 3;
  int w = threadIdx.x >> 6, l = threadIdx.x & 63;
  int d = g * 4 + w;
  if (d >= N) return;
  int base = rowptr[d], cnt = rowptr[d + 1] - base;
  const int* sp = csr_src + base;
  const float* asp = a_src1h + (size_t)head * N;
  const __half* hp = h1p + (size_t)head * N * 32;
  float adst = a_dst1h[(size_t)head * N + d];
  int slot = l >> 3, lp = l & 7;
  float4 acc = make_float4(0.f, 0.f, 0.f, 0.f);
  float p = 0.f;
  int e = slot;
  for (; e + 24 < cnt; e += 32) {
    int s[4];
    H4 v[4];
    float xv[4];
#pragma unroll
    for (int j = 0; j < 4; j++) s[j] = sp[e + 8 * j];
#pragma unroll
    for (int j = 0; j < 4; j++)
      v[j] = *(const H4*)(hp + (size_t)s[j] * 32 + lp * 4);
#pragma unroll
    for (int j = 0; j < 4; j++) {
      float ee = asp[s[j]] + adst;
      ee = LEAKY(ee);
      xv[j] = __expf(ee);
      p += xv[j];
    }
#pragma unroll
    for (int j = 0; j < 4; j++) {
      float2 f0 = __half22float2(v[j].a), f1 = __half22float2(v[j].b);
      acc.x = fmaf(f0.x, xv[j], acc.x);
      acc.y = fmaf(f0.y, xv[j], acc.y);
      acc.z = fmaf(f1.x, xv[j], acc.z);
      acc.w = fmaf(f1.y, xv[j], acc.w);
    }
  }
  for (; e < cnt; e += 8) {
    int s = sp[e];
    float ee = asp[s] + adst;
    ee = LEAKY(ee);
    float a = __expf(ee);
    p += a;
    H4 v = *(const H4*)(hp + (size_t)s * 32 + lp * 4);
    float2 f0 = __half22float2(v.a), f1 = __half22float2(v.b);
    acc.x = fmaf(f0.x, a, acc.x);
    acc.y = fmaf(f0.y, a, acc.y);
    acc.z = fmaf(f1.x, a, acc.z);
    acc.w = fmaf(f1.y, a, acc.w);
  }
  // reduce across the 8 slots (xor over slot bits 3,4,5)
#pragma unroll
  for (int o = 8; o < 64; o <<= 1) {
    acc.x += __shfl_xor(acc.x, o, 64);
    acc.y += __shfl_xor(acc.y, o, 64);
    acc.z += __shfl_xor(acc.z, o, 64);
    acc.w += __shfl_xor(acc.w, o, 64);
    p += __shfl_xor(p, o, 64);
  }
  if (l < 8) {
    float rinv = 1.f / (p + 1e-16f);
    float4 bb = *(const float4*)(bias + head * 32 + lp * 4);
    float ox = fmaf(acc.x, rinv, bb.x), oy = fmaf(acc.y, rinv, bb.y);
    float oz = fmaf(acc.z, rinv, bb.z), ow = fmaf(acc.w, rinv, bb.w);
    ox = ox > 0.f ? ox : expm1f(ox);
    oy = oy > 0.f ? oy : expm1f(oy);
    oz = oz > 0.f ? oz : expm1f(oz);
    ow = ow > 0.f ? ow : expm1f(ow);
    H4 hv;
    hv.a = __floats2half2_rn(ox, oy);
    hv.b = __floats2half2_rn(oz, ow);
    *(H4*)(h_act + (size_t)d * 256 + head * 32 + lp * 4) = hv;
  }
}

// ------- K6: gemm2 ---------------------------------------------------------
__global__ __launch_bounds__(256) void gemm2_kernel(
    const _Float16* __restrict__ h_act, const _Float16* __restrict__ Bt2,
    _Float16* __restrict__ h2p, const float* __restrict__ att_src2,
    const float* __restrict__ att_dst2, float* __restrict__ a_src2,
    float* __restrict__ a_dst2, int N) {
  gemm_tile<256, 64, false>(h_act, Bt2, h2p, att_src2, att_dst2, a_src2,
                            a_dst2, N, blockIdx.x, 0, threadIdx.x >> 6,
                            threadIdx.x & 63);
}

// ------- K7: agg2 — wave = (dst, 32-ch slice), XCD-affine (blockIdx&1) -----
__global__ __launch_bounds__(256) void agg2_kernel(
    const int* __restrict__ rowptr, const int* __restrict__ csr_src,
    const float* __restrict__ a_src2, const float* __restrict__ a_dst2,
    const __half* __restrict__ h2p, const float* __restrict__ bias,
    float* __restrict__ out, int N) {
  int b = blockIdx.x;
  int slice = b & 1, g = b >> 1;
  int w = threadIdx.x >> 6, l = threadIdx.x & 63;
  int d = g * 4 + w;
  if (d >= N) return;
  int base = rowptr[d], cnt = rowptr[d + 1] - base;
  const int* sp = csr_src + base;
  const __half* hp = h2p + (size_t)slice * N * 32;
  float adst = a_dst2[d];
  int slot = l >> 3, lp = l & 7;
  float4 acc = make_float4(0.f, 0.f, 0.f, 0.f);
  float p = 0.f;
  int e = slot;
  for (; e + 24 < cnt; e += 32) {
    int s[4];
    H4 v[4];
    float xv[4];
#pragma unroll
    for (int j = 0; j < 4; j++) s[j] = sp[e + 8 * j];
#pragma unroll
    for (int j = 0; j < 4; j++)
      v[j] = *(const H4*)(hp + (size_t)s[j] * 32 + lp * 4);
#pragma unroll
    for (int j = 0; j < 4; j++) {
      float ee = a_src2[s[j]] + adst;
      ee = LEAKY(ee);
      xv[j] = __expf(ee);
      p += xv[j];
    }
#pragma unroll
    for (int j = 0; j < 4; j++) {
      float2 f0 = __half22float2(v[j].a), f1 = __half22float2(v[j].b);
      acc.x = fmaf(f0.x, xv[j], acc.x);
      acc.y = fmaf(f0.y, xv[j], acc.y);
      acc.z = fmaf(f1.x, xv[j], acc.z);
      acc.w = fmaf(f1.y, xv[j], acc.w);
    }
  }
  for (; e < cnt; e += 8) {
    int s = sp[e];
    float ee = a_src2[s] + adst;
    ee = LEAKY(ee);
    float a = __expf(ee);
    p += a;
    H4 v = *(const H4*)(hp + (size_t)s * 32 + lp * 4);
    float2 f0 = __half22float2(v.a), f1 = __half22float2(v.b);
    acc.x = fmaf(f0.x, a, acc.x);
    acc.y = fmaf(f0.y, a, acc.y);
    acc.z = fmaf(f1.x, a, acc.z);
    acc.w = fmaf(f1.y, a, acc.w);
  }
#pragma unroll
  for (int o = 8; o < 64; o <<= 1) {
    acc.x += __shfl_xor(acc.x, o, 64);
    acc.y += __shfl_xor(acc.y, o, 64);
    acc.z += __shfl_xor(acc.z, o, 64);
    acc.w += __shfl_xor(acc.w, o, 64);
    p += __shfl_xor(p, o, 64);
  }
  if (l < 8) {
    float rinv = 1.f / (p + 1e-16f);
    float4 bb = *(const float4*)(bias + slice * 32 + lp * 4);
    *(float4*)(out + (size_t)d * 64 + slice * 32 + lp * 4) =
        make_float4(fmaf(acc.x, rinv, bb.x), fmaf(acc.y, rinv, bb.y),
                    fmaf(acc.z, rinv, bb.z), fmaf(acc.w, rinv, bb.w));
  }
}

// ---------------------------------------------------------------------------
extern "C" void kernel_launch(void* const* d_in, const int* in_sizes, int n_in,
                              void* d_out, int out_size, void* d_ws, size_t ws_size,
                              hipStream_t stream) {
  const float* x        = (const float*)d_in[0];
  const int*   ei       = (const int*)d_in[1];
  const float* W1       = (const float*)d_in[3];
  const float* att_src1 = (const float*)d_in[4];
  const float* att_dst1 = (const float*)d_in[5];
  const float* bias1    = (const float*)d_in[6];
  const float* W2       = (const float*)d_in[7];
  const float* att_src2 = (const float*)d_in[8];
  const float* att_dst2 = (const float*)d_in[9];
  const float* bias2    = (const float*)d_in[10];
  float* out = (float*)d_out;

  int N = in_sizes[0] / 128;
  int E = in_sizes[1] / 2;
  int Etot = E + N;
  int nb = (N + 255) / 256;  // 196 <= 256 (scan3 requirement)

  char* ws = (char*)d_ws;
  size_t off = 0;
  auto carve = [&](size_t bytes) -> void* {
    void* p = ws + off;
    off += (bytes + 255) & ~(size_t)255;
    return p;
  };
  _Float16* Bt1   = (_Float16*)carve((size_t)256 * 128 * 2);
  _Float16* Bt2   = (_Float16*)carve((size_t)64 * 256 * 2);
  _Float16* h1p   = (_Float16*)carve((size_t)N * 256 * 2);  // [8][N][32]
  _Float16* h2p   = (_Float16*)carve((size_t)N * 64 * 2);   // [2][N][32]
  _Float16* h_act = (_Float16*)carve((size_t)N * 256 * 2);  // [N][256]
  float* a_src1h = (float*)carve((size_t)N * 8 * 4);        // [8][N]
  float* a_dst1h = (float*)carve((size_t)N * 8 * 4);
  float* a_src2  = (float*)carve((size_t)N * 4);
  float* a_dst2  = (float*)carve((size_t)N * 4);
  int* rowptr    = (int*)carve((size_t)(N + 1) * 4);
  int* cursor    = (int*)carve((size_t)N * 4);
  int* deg       = (int*)carve((size_t)N * 4);
  int* bsum      = (int*)carve((size_t)nb * 4);
  int* csr_src   = (int*)carve((size_t)Etot * 4);
  (void)ws_size; (void)n_in; (void)out_size;

  hipMemsetAsync(deg, 0, (size_t)N * 4, stream);
  // K1: W transposes || degree histogram
  {
    int grid = 192 + (Etot + 255) / 256;
    prep_hist_kernel<<<grid, 256, 0, stream>>>(W1, W2, ei, Bt1, Bt2, deg, N, E);
  }
  // K2: gemm1 (MFMA, fp32->fp16 in-register A) || scan1 chunk sums
  int tiles1 = ((N + 127) / 128) * 4;
  gemm1_scan1_kernel<<<tiles1 + nb, 256, 0, stream>>>(
      x, Bt1, h1p, att_src1, att_dst1, a_src1h, a_dst1h, deg, bsum, N, tiles1);
  // K3: scan -> rowptr/cursor
  scan3_kernel<<<nb, 256, 0, stream>>>(deg, bsum, rowptr, cursor, N);
  // K4: scatter
  scatter_kernel<<<(Etot + 255) / 256, 256, 0, stream>>>(ei, E, N, cursor, csr_src);
  // K5: agg1 (+bias+ELU, fp16 flat out)
  agg1_kernel<<<((N + 3) / 4) * 8, 256, 0, stream>>>(
      rowptr, csr_src, a_src1h, a_dst1h, (const __half*)h1p, bias1, h_act, N);
  // K6: gemm2 (MFMA)
  gemm2_kernel<<<(N + 127) / 128, 256, 0, stream>>>(
      h_act, Bt2, h2p, att_src2, att_dst2, a_src2, a_dst2, N);
  // K7: agg2 (+bias)
  agg2_kernel<<<((N + 3) / 4) * 2, 256, 0, stream>>>(
      rowptr, csr_src, a_src2, a_dst2, (const __half*)h2p, bias2, out, N);
}

// Round 11
// 371.848 us; speedup vs baseline: 2.4976x; 1.1573x over previous
//
#include <hip/hip_runtime.h>
#include <hip/hip_fp16.h>
#include <math.h>

// ---------------------------------------------------------------------------
// 2-layer GAT on MI355X (gfx950).
// L1: in=128, H=8, C=32 (concat->256) +bias1, ELU.  L2: in=256, H=1, C=64 +bias2.
// R11: flat wave-per-dst aggregation restored (R10's head-sliced waves paid
// 8x preamble/epilogue per dst -> 171us @94% VALU; flat R8 shape = 76us).
// New: exp-dedup lane-role split in agg1/agg2 (one exp per (edge,head) per
// wave, alpha distributed by shuffle) ~35% VALU cut; scan1+scan3 fused into
// one self-carry kernel; gemm1 || scatter merged (independent after scan).
// 1 memset + 6 kernels (was 9 nodes).
// ---------------------------------------------------------------------------

#define LEAKY(e) ((e) > 0.f ? (e) : 0.2f * (e))

struct __align__(8) H4 { __half2 a, b; };  // 4 halves

typedef _Float16 half8 __attribute__((ext_vector_type(8)));
typedef float f32x4 __attribute__((ext_vector_type(4)));

// ------- MFMA GEMM tile + fused attention coefficients (device fn) ---------
// C[n,NTOT] = A[n,K] @ B[K,NTOT]; A row-major (fp32 if AF32 else fp16),
// Bt fp16 [NTOT][K]. Tile 128x64 per 4-wave block; wave tile 32x64.
// Flat fp16 C out; a_src/a_dst: NTOT=256 -> [n][8] interleaved; NTOT=64 -> [n].
template <int K, int NTOT, bool AF32>
__device__ __forceinline__ void gemm_tile(
    const void* __restrict__ Av, const _Float16* __restrict__ Bt,
    _Float16* __restrict__ Ch, const float* __restrict__ att_src,
    const float* __restrict__ att_dst, float* __restrict__ a_src,
    float* __restrict__ a_dst, int n, int bx, int by, int w, int l) {
  int lm = l & 15, lq = l >> 4;
  int m0 = bx * 128 + w * 32;
  int c0 = by * 64;
  int ra = m0 + lm;      if (ra > n - 1) ra = n - 1;
  int rb = m0 + 16 + lm; if (rb > n - 1) rb = n - 1;
  f32x4 acc[2][4];
#pragma unroll
  for (int mt = 0; mt < 2; mt++)
#pragma unroll
    for (int nt = 0; nt < 4; nt++) acc[mt][nt] = (f32x4){0.f, 0.f, 0.f, 0.f};
  for (int k0 = 0; k0 < K; k0 += 32) {
    half8 a0, a1;
    if (AF32) {
      const float* pa = (const float*)Av + (size_t)ra * K + k0 + lq * 8;
      const float* pb = (const float*)Av + (size_t)rb * K + k0 + lq * 8;
      float4 u0 = *(const float4*)pa, u1 = *(const float4*)(pa + 4);
      float4 w0 = *(const float4*)pb, w1 = *(const float4*)(pb + 4);
      a0[0] = (_Float16)u0.x; a0[1] = (_Float16)u0.y;
      a0[2] = (_Float16)u0.z; a0[3] = (_Float16)u0.w;
      a0[4] = (_Float16)u1.x; a0[5] = (_Float16)u1.y;
      a0[6] = (_Float16)u1.z; a0[7] = (_Float16)u1.w;
      a1[0] = (_Float16)w0.x; a1[1] = (_Float16)w0.y;
      a1[2] = (_Float16)w0.z; a1[3] = (_Float16)w0.w;
      a1[4] = (_Float16)w1.x; a1[5] = (_Float16)w1.y;
      a1[6] = (_Float16)w1.z; a1[7] = (_Float16)w1.w;
    } else {
      a0 = *(const half8*)((const _Float16*)Av + (size_t)ra * K + k0 + lq * 8);
      a1 = *(const half8*)((const _Float16*)Av + (size_t)rb * K + k0 + lq * 8);
    }
    half8 b0 = *(const half8*)(Bt + (size_t)(c0 + 0 + lm) * K + k0 + lq * 8);
    half8 b1 = *(const half8*)(Bt + (size_t)(c0 + 16 + lm) * K + k0 + lq * 8);
    half8 b2 = *(const half8*)(Bt + (size_t)(c0 + 32 + lm) * K + k0 + lq * 8);
    half8 b3 = *(const half8*)(Bt + (size_t)(c0 + 48 + lm) * K + k0 + lq * 8);
    acc[0][0] = __builtin_amdgcn_mfma_f32_16x16x32_f16(a0, b0, acc[0][0], 0, 0, 0);
    acc[0][1] = __builtin_amdgcn_mfma_f32_16x16x32_f16(a0, b1, acc[0][1], 0, 0, 0);
    acc[0][2] = __builtin_amdgcn_mfma_f32_16x16x32_f16(a0, b2, acc[0][2], 0, 0, 0);
    acc[0][3] = __builtin_amdgcn_mfma_f32_16x16x32_f16(a0, b3, acc[0][3], 0, 0, 0);
    acc[1][0] = __builtin_amdgcn_mfma_f32_16x16x32_f16(a1, b0, acc[1][0], 0, 0, 0);
    acc[1][1] = __builtin_amdgcn_mfma_f32_16x16x32_f16(a1, b1, acc[1][1], 0, 0, 0);
    acc[1][2] = __builtin_amdgcn_mfma_f32_16x16x32_f16(a1, b2, acc[1][2], 0, 0, 0);
    acc[1][3] = __builtin_amdgcn_mfma_f32_16x16x32_f16(a1, b3, acc[1][3], 0, 0, 0);
  }
  float as_[4], ad_[4];
#pragma unroll
  for (int nt = 0; nt < 4; nt++) {
    as_[nt] = att_src[c0 + nt * 16 + lm];
    ad_[nt] = att_dst[c0 + nt * 16 + lm];
  }
#pragma unroll
  for (int mt = 0; mt < 2; mt++) {
#pragma unroll
    for (int i = 0; i < 4; i++) {
      int gr = m0 + mt * 16 + lq * 4 + i;
      bool ok = gr < n;
      if (ok) {
#pragma unroll
        for (int nt = 0; nt < 4; nt++)
          Ch[(size_t)gr * NTOT + c0 + nt * 16 + lm] = (_Float16)acc[mt][nt][i];
      }
      float p0 = acc[mt][0][i] * as_[0] + acc[mt][1][i] * as_[1];
      float p1 = acc[mt][2][i] * as_[2] + acc[mt][3][i] * as_[3];
      float q0 = acc[mt][0][i] * ad_[0] + acc[mt][1][i] * ad_[1];
      float q1 = acc[mt][2][i] * ad_[2] + acc[mt][3][i] * ad_[3];
#pragma unroll
      for (int o = 1; o < 16; o <<= 1) {
        p0 += __shfl_xor(p0, o, 64);
        p1 += __shfl_xor(p1, o, 64);
        q0 += __shfl_xor(q0, o, 64);
        q1 += __shfl_xor(q1, o, 64);
      }
      if (lm == 0 && ok) {
        if (NTOT == 256) {
          int h0 = c0 >> 5;
          a_src[(size_t)gr * 8 + h0] = p0;
          a_src[(size_t)gr * 8 + h0 + 1] = p1;
          a_dst[(size_t)gr * 8 + h0] = q0;
          a_dst[(size_t)gr * 8 + h0 + 1] = q1;
        } else {
          a_src[gr] = p0 + p1;
          a_dst[gr] = q0 + q1;
        }
      }
    }
  }
}

// ------- K1: W transposes || degree histogram ------------------------------
__global__ __launch_bounds__(256) void prep_hist_kernel(
    const float* __restrict__ W1, const float* __restrict__ W2,
    const int* __restrict__ ei, _Float16* __restrict__ Bt1,
    _Float16* __restrict__ Bt2, int* __restrict__ deg, int N, int E) {
  int t = threadIdx.x, b = blockIdx.x;
  if (b < 128) {
    int o = b * 256 + t;  // o = n*128 + k
    int nn = o >> 7, kk = o & 127;
    Bt1[o] = (_Float16)W1[kk * 256 + nn];
  } else if (b < 192) {
    int o = (b - 128) * 256 + t;  // o = n*256 + k
    int nn = o >> 8, kk = o & 255;
    Bt2[o] = (_Float16)W2[kk * 64 + nn];
  } else {
    int idx = (b - 192) * 256 + t;
    if (idx < E + N) {
      int d = (idx < E) ? ei[E + idx] : (idx - E);
      atomicAdd(&deg[d], 1);
    }
  }
}

// ------- K2: fused scan (self-carry) -> rowptr, cursor ---------------------
// block b: carry = sum(deg[0 .. b*256)) computed locally (L2-resident reads).
__global__ __launch_bounds__(256) void scan_kernel(
    const int* __restrict__ deg, int* __restrict__ rowptr,
    int* __restrict__ cursor, int n) {
  __shared__ int sb[256];
  __shared__ int ws[4];
  int t = threadIdx.x, b = blockIdx.x;
  int pre = 0;
  for (int i = t; i < b * 256; i += 256) pre += deg[i];
#pragma unroll
  for (int o = 32; o; o >>= 1) pre += __shfl_xor(pre, o, 64);
  if ((t & 63) == 0) ws[t >> 6] = pre;
  __syncthreads();
  int carry = ws[0] + ws[1] + ws[2] + ws[3];
  int i = b * 256 + t;
  int v = (i < n) ? deg[i] : 0;
  sb[t] = v;
  __syncthreads();
  int x = v;
  for (int off = 1; off < 256; off <<= 1) {
    int y = (t >= off) ? sb[t - off] : 0;
    __syncthreads();
    x += y;
    sb[t] = x;
    __syncthreads();
  }
  int excl = x - v + carry;
  if (i < n) {
    rowptr[i] = excl;
    cursor[i] = excl;
  }
  if (i == n - 1) rowptr[n] = excl + v;
}

// ------- K3: gemm1 tiles || scatter (independent after scan) ---------------
__global__ __launch_bounds__(256) void gemm1_scatter_kernel(
    const float* __restrict__ x, const _Float16* __restrict__ Bt1,
    _Float16* __restrict__ h1h, const float* __restrict__ att_src1,
    const float* __restrict__ att_dst1, float* __restrict__ a_src1,
    float* __restrict__ a_dst1, int N, int tiles1, const int* __restrict__ ei,
    int E, int* __restrict__ cursor, int* __restrict__ csr_src) {
  int b = blockIdx.x, t = threadIdx.x;
  if (b < tiles1) {
    gemm_tile<128, 256, true>(x, Bt1, h1h, att_src1, att_dst1, a_src1,
                              a_dst1, N, b >> 2, b & 3, t >> 6, t & 63);
  } else {
    int idx = (b - tiles1) * 256 + t;
    if (idx >= E + N) return;
    int s, d;
    if (idx < E) {
      s = ei[idx];
      d = ei[E + idx];
    } else {
      s = d = idx - E;
    }
    int pos = atomicAdd(&cursor[d], 1);
    csr_src[pos] = s;
  }
}

// ------- K4: agg1 — wave per dst, exp-dedup lane roles ---------------------
// Role A (exp): lane l handles (edge i+(l>>3), head l&7) -> one exp per
// (edge,head) per wave. Role B (fma): lane l owns channels 4l..4l+3
// (head l>>3); alpha fetched by shuffle from lane j*8+(l>>3).
__global__ __launch_bounds__(256) void agg1_kernel(
    const int* __restrict__ rowptr, const int* __restrict__ csr_src,
    const float* __restrict__ a_src1, const float* __restrict__ a_dst1,
    const __half* __restrict__ h1h, const float* __restrict__ bias,
    _Float16* __restrict__ h_act, int N) {
  int w = threadIdx.x >> 6, l = threadIdx.x & 63;
  int d = blockIdx.x * 4 + w;
  if (d >= N) return;
  int base = rowptr[d], cnt = rowptr[d + 1] - base;
  const int* sp = csr_src + base;
  int hh = l >> 3;  // owned-channel head / role-A edge offset
  int he = l & 7;   // role-A head
  float adst_e = a_dst1[(size_t)d * 8 + he];
  float4 acc = make_float4(0.f, 0.f, 0.f, 0.f);
  float p = 0.f;
  for (int i = 0; i < cnt; i += 8) {
    int ei = i + hh;
    int ec = ei < cnt ? ei : cnt - 1;
    int s_e = sp[ec];
    float e = a_src1[(size_t)s_e * 8 + he] + adst_e;
    e = LEAKY(e);
    float xv = (ei < cnt) ? __expf(e) : 0.f;
    p += xv;
#pragma unroll
    for (int j = 0; j < 8; j++) {
      if (i + j >= cnt) break;
      float a = __shfl(xv, j * 8 + hh, 64);
      int s = __shfl(s_e, j * 8, 64);
      H4 v = *(const H4*)(h1h + (size_t)s * 256 + 4 * l);
      float2 f0 = __half22float2(v.a), f1 = __half22float2(v.b);
      acc.x = fmaf(f0.x, a, acc.x);
      acc.y = fmaf(f0.y, a, acc.y);
      acc.z = fmaf(f1.x, a, acc.z);
      acc.w = fmaf(f1.y, a, acc.w);
    }
  }
  // denominator per head (l&7): sum across the 8 edge-offset groups
  p += __shfl_xor(p, 8, 64);
  p += __shfl_xor(p, 16, 64);
  p += __shfl_xor(p, 32, 64);
  float rinv = 1.f / (__shfl(p, hh, 64) + 1e-16f);  // lane hh holds head hh
  float4 bb = *(const float4*)(bias + 4 * l);
  float ox = fmaf(acc.x, rinv, bb.x), oy = fmaf(acc.y, rinv, bb.y);
  float oz = fmaf(acc.z, rinv, bb.z), ow = fmaf(acc.w, rinv, bb.w);
  ox = ox > 0.f ? ox : expm1f(ox);
  oy = oy > 0.f ? oy : expm1f(oy);
  oz = oz > 0.f ? oz : expm1f(oz);
  ow = ow > 0.f ? ow : expm1f(ow);
  H4 hv;
  hv.a = __floats2half2_rn(ox, oy);
  hv.b = __floats2half2_rn(oz, ow);
  *(H4*)(h_act + (size_t)d * 256 + 4 * l) = hv;
}

// ------- K5: gemm2 ---------------------------------------------------------
__global__ __launch_bounds__(256) void gemm2_kernel(
    const _Float16* __restrict__ h_act, const _Float16* __restrict__ Bt2,
    _Float16* __restrict__ h2h, const float* __restrict__ att_src2,
    const float* __restrict__ att_dst2, float* __restrict__ a_src2,
    float* __restrict__ a_dst2, int N) {
  gemm_tile<256, 64, false>(h_act, Bt2, h2h, att_src2, att_dst2, a_src2,
                            a_dst2, N, blockIdx.x, 0, threadIdx.x >> 6,
                            threadIdx.x & 63);
}

// ------- K6: agg2 — wave per dst, exp-dedup (64 edges/step) ----------------
__global__ __launch_bounds__(256) void agg2_kernel(
    const int* __restrict__ rowptr, const int* __restrict__ csr_src,
    const float* __restrict__ a_src2, const float* __restrict__ a_dst2,
    const __half* __restrict__ h2h, const float* __restrict__ bias,
    float* __restrict__ out, int N) {
  int w = threadIdx.x >> 6, l = threadIdx.x & 63;
  int d = blockIdx.x * 4 + w;
  if (d >= N) return;
  int base = rowptr[d], cnt = rowptr[d + 1] - base;
  const int* sp = csr_src + base;
  float adst = a_dst2[d];
  int e2 = l >> 5;          // edge slot 0/1
  int c2 = (l & 31) * 2;    // channel pair
  float2 acc = make_float2(0.f, 0.f);
  float p = 0.f;
  for (int i = 0; i < cnt; i += 64) {
    int ei = i + l;
    int ec = ei < cnt ? ei : cnt - 1;
    int s_e = sp[ec];
    float e = a_src2[s_e] + adst;
    e = LEAKY(e);
    float xv = (ei < cnt) ? __expf(e) : 0.f;
    p += xv;
#pragma unroll 8
    for (int j = 0; j < 32; j++) {
      if (i + 2 * j >= cnt) break;
      float a = __shfl(xv, 2 * j + e2, 64);     // 0 if edge OOB (xv=0)
      int s = __shfl(s_e, 2 * j + e2, 64);      // clamped-valid if OOB
      float2 f = __half22float2(*(const __half2*)(h2h + (size_t)s * 64 + c2));
      acc.x = fmaf(f.x, a, acc.x);
      acc.y = fmaf(f.y, a, acc.y);
    }
  }
#pragma unroll
  for (int o = 32; o; o >>= 1) p += __shfl_xor(p, o, 64);
  acc.x += __shfl_xor(acc.x, 32, 64);
  acc.y += __shfl_xor(acc.y, 32, 64);
  if (l < 32) {
    float rinv = 1.f / (p + 1e-16f);
    float2 bb = *(const float2*)(bias + c2);
    *(float2*)(out + (size_t)d * 64 + c2) =
        make_float2(fmaf(acc.x, rinv, bb.x), fmaf(acc.y, rinv, bb.y));
  }
}

// ---------------------------------------------------------------------------
extern "C" void kernel_launch(void* const* d_in, const int* in_sizes, int n_in,
                              void* d_out, int out_size, void* d_ws, size_t ws_size,
                              hipStream_t stream) {
  const float* x        = (const float*)d_in[0];
  const int*   ei       = (const int*)d_in[1];
  const float* W1       = (const float*)d_in[3];
  const float* att_src1 = (const float*)d_in[4];
  const float* att_dst1 = (const float*)d_in[5];
  const float* bias1    = (const float*)d_in[6];
  const float* W2       = (const float*)d_in[7];
  const float* att_src2 = (const float*)d_in[8];
  const float* att_dst2 = (const float*)d_in[9];
  const float* bias2    = (const float*)d_in[10];
  float* out = (float*)d_out;

  int N = in_sizes[0] / 128;
  int E = in_sizes[1] / 2;
  int Etot = E + N;
  int nb = (N + 255) / 256;

  char* ws = (char*)d_ws;
  size_t off = 0;
  auto carve = [&](size_t bytes) -> void* {
    void* p = ws + off;
    off += (bytes + 255) & ~(size_t)255;
    return p;
  };
  _Float16* Bt1   = (_Float16*)carve((size_t)256 * 128 * 2);
  _Float16* Bt2   = (_Float16*)carve((size_t)64 * 256 * 2);
  _Float16* h1h   = (_Float16*)carve((size_t)N * 256 * 2);  // [N][256]
  _Float16* h2h   = (_Float16*)carve((size_t)N * 64 * 2);   // [N][64]
  _Float16* h_act = (_Float16*)carve((size_t)N * 256 * 2);  // [N][256]
  float* a_src1  = (float*)carve((size_t)N * 8 * 4);        // [N][8]
  float* a_dst1  = (float*)carve((size_t)N * 8 * 4);
  float* a_src2  = (float*)carve((size_t)N * 4);
  float* a_dst2  = (float*)carve((size_t)N * 4);
  int* rowptr    = (int*)carve((size_t)(N + 1) * 4);
  int* cursor    = (int*)carve((size_t)N * 4);
  int* deg       = (int*)carve((size_t)N * 4);
  int* csr_src   = (int*)carve((size_t)Etot * 4);
  (void)ws_size; (void)n_in; (void)out_size;

  hipMemsetAsync(deg, 0, (size_t)N * 4, stream);
  // K1: W transposes || degree histogram
  {
    int grid = 192 + (Etot + 255) / 256;
    prep_hist_kernel<<<grid, 256, 0, stream>>>(W1, W2, ei, Bt1, Bt2, deg, N, E);
  }
  // K2: fused scan -> rowptr/cursor
  scan_kernel<<<nb, 256, 0, stream>>>(deg, rowptr, cursor, N);
  // K3: gemm1 (MFMA) || scatter
  int tiles1 = ((N + 127) / 128) * 4;
  {
    int grid = tiles1 + (Etot + 255) / 256;
    gemm1_scatter_kernel<<<grid, 256, 0, stream>>>(
        x, Bt1, h1h, att_src1, att_dst1, a_src1, a_dst1, N, tiles1, ei, E,
        cursor, csr_src);
  }
  // K4: agg1 (+bias+ELU, fp16 out)
  agg1_kernel<<<(N + 3) / 4, 256, 0, stream>>>(
      rowptr, csr_src, a_src1, a_dst1, (const __half*)h1h, bias1, h_act, N);
  // K5: gemm2 (MFMA)
  gemm2_kernel<<<(N + 127) / 128, 256, 0, stream>>>(
      h_act, Bt2, h2h, att_src2, att_dst2, a_src2, a_dst2, N);
  // K6: agg2 (+bias)
  agg2_kernel<<<(N + 3) / 4, 256, 0, stream>>>(
      rowptr, csr_src, a_src2, a_dst2, (const __half*)h2h, bias2, out, N);
}

// Round 12
// 316.865 us; speedup vs baseline: 2.9310x; 1.1735x over previous
//
#include <hip/hip_runtime.h>
#include <hip/hip_fp16.h>
#include <math.h>

// ---------------------------------------------------------------------------
// 2-layer GAT on MI355X (gfx950).
// L1: in=128, H=8, C=32 (concat->256) +bias1, ELU.  L2: in=256, H=1, C=64 +bias2.
// R12: aggs reverted to R8's proven shape (direct per-lane exp, 8-deep batched
// gathers — R11's shuffle-dedup broke load batching, +55us). Kept: fused
// self-carry scan, gemm1||scatter merge. New: atomic-free scatter — the hist
// atomicAdd's return value is the edge's rank within its dst row; scatter
// computes pos = rowptr[d] + edge_rank[i] (no cursor array, no 2nd atomic
// round). 1 memset + 6 kernels.
// ---------------------------------------------------------------------------

#define LEAKY(e) ((e) > 0.f ? (e) : 0.2f * (e))

struct __align__(8) H4 { __half2 a, b; };  // 4 halves

typedef _Float16 half8 __attribute__((ext_vector_type(8)));
typedef float f32x4 __attribute__((ext_vector_type(4)));

// ------- MFMA GEMM tile + fused attention coefficients (device fn) ---------
// C[n,NTOT] = A[n,K] @ B[K,NTOT]; A row-major (fp32 if AF32 else fp16),
// Bt fp16 [NTOT][K]. Tile 128x64 per 4-wave block; wave tile 32x64.
// Flat fp16 C out; a_src/a_dst: NTOT=256 -> [n][8]; NTOT=64 -> [n].
template <int K, int NTOT, bool AF32>
__device__ __forceinline__ void gemm_tile(
    const void* __restrict__ Av, const _Float16* __restrict__ Bt,
    _Float16* __restrict__ Ch, const float* __restrict__ att_src,
    const float* __restrict__ att_dst, float* __restrict__ a_src,
    float* __restrict__ a_dst, int n, int bx, int by, int w, int l) {
  int lm = l & 15, lq = l >> 4;
  int m0 = bx * 128 + w * 32;
  int c0 = by * 64;
  int ra = m0 + lm;      if (ra > n - 1) ra = n - 1;
  int rb = m0 + 16 + lm; if (rb > n - 1) rb = n - 1;
  f32x4 acc[2][4];
#pragma unroll
  for (int mt = 0; mt < 2; mt++)
#pragma unroll
    for (int nt = 0; nt < 4; nt++) acc[mt][nt] = (f32x4){0.f, 0.f, 0.f, 0.f};
  for (int k0 = 0; k0 < K; k0 += 32) {
    half8 a0, a1;
    if (AF32) {
      const float* pa = (const float*)Av + (size_t)ra * K + k0 + lq * 8;
      const float* pb = (const float*)Av + (size_t)rb * K + k0 + lq * 8;
      float4 u0 = *(const float4*)pa, u1 = *(const float4*)(pa + 4);
      float4 w0 = *(const float4*)pb, w1 = *(const float4*)(pb + 4);
      a0[0] = (_Float16)u0.x; a0[1] = (_Float16)u0.y;
      a0[2] = (_Float16)u0.z; a0[3] = (_Float16)u0.w;
      a0[4] = (_Float16)u1.x; a0[5] = (_Float16)u1.y;
      a0[6] = (_Float16)u1.z; a0[7] = (_Float16)u1.w;
      a1[0] = (_Float16)w0.x; a1[1] = (_Float16)w0.y;
      a1[2] = (_Float16)w0.z; a1[3] = (_Float16)w0.w;
      a1[4] = (_Float16)w1.x; a1[5] = (_Float16)w1.y;
      a1[6] = (_Float16)w1.z; a1[7] = (_Float16)w1.w;
    } else {
      a0 = *(const half8*)((const _Float16*)Av + (size_t)ra * K + k0 + lq * 8);
      a1 = *(const half8*)((const _Float16*)Av + (size_t)rb * K + k0 + lq * 8);
    }
    half8 b0 = *(const half8*)(Bt + (size_t)(c0 + 0 + lm) * K + k0 + lq * 8);
    half8 b1 = *(const half8*)(Bt + (size_t)(c0 + 16 + lm) * K + k0 + lq * 8);
    half8 b2 = *(const half8*)(Bt + (size_t)(c0 + 32 + lm) * K + k0 + lq * 8);
    half8 b3 = *(const half8*)(Bt + (size_t)(c0 + 48 + lm) * K + k0 + lq * 8);
    acc[0][0] = __builtin_amdgcn_mfma_f32_16x16x32_f16(a0, b0, acc[0][0], 0, 0, 0);
    acc[0][1] = __builtin_amdgcn_mfma_f32_16x16x32_f16(a0, b1, acc[0][1], 0, 0, 0);
    acc[0][2] = __builtin_amdgcn_mfma_f32_16x16x32_f16(a0, b2, acc[0][2], 0, 0, 0);
    acc[0][3] = __builtin_amdgcn_mfma_f32_16x16x32_f16(a0, b3, acc[0][3], 0, 0, 0);
    acc[1][0] = __builtin_amdgcn_mfma_f32_16x16x32_f16(a1, b0, acc[1][0], 0, 0, 0);
    acc[1][1] = __builtin_amdgcn_mfma_f32_16x16x32_f16(a1, b1, acc[1][1], 0, 0, 0);
    acc[1][2] = __builtin_amdgcn_mfma_f32_16x16x32_f16(a1, b2, acc[1][2], 0, 0, 0);
    acc[1][3] = __builtin_amdgcn_mfma_f32_16x16x32_f16(a1, b3, acc[1][3], 0, 0, 0);
  }
  float as_[4], ad_[4];
#pragma unroll
  for (int nt = 0; nt < 4; nt++) {
    as_[nt] = att_src[c0 + nt * 16 + lm];
    ad_[nt] = att_dst[c0 + nt * 16 + lm];
  }
#pragma unroll
  for (int mt = 0; mt < 2; mt++) {
#pragma unroll
    for (int i = 0; i < 4; i++) {
      int gr = m0 + mt * 16 + lq * 4 + i;
      bool ok = gr < n;
      if (ok) {
#pragma unroll
        for (int nt = 0; nt < 4; nt++)
          Ch[(size_t)gr * NTOT + c0 + nt * 16 + lm] = (_Float16)acc[mt][nt][i];
      }
      float p0 = acc[mt][0][i] * as_[0] + acc[mt][1][i] * as_[1];
      float p1 = acc[mt][2][i] * as_[2] + acc[mt][3][i] * as_[3];
      float q0 = acc[mt][0][i] * ad_[0] + acc[mt][1][i] * ad_[1];
      float q1 = acc[mt][2][i] * ad_[2] + acc[mt][3][i] * ad_[3];
#pragma unroll
      for (int o = 1; o < 16; o <<= 1) {
        p0 += __shfl_xor(p0, o, 64);
        p1 += __shfl_xor(p1, o, 64);
        q0 += __shfl_xor(q0, o, 64);
        q1 += __shfl_xor(q1, o, 64);
      }
      if (lm == 0 && ok) {
        if (NTOT == 256) {
          int h0 = c0 >> 5;
          a_src[(size_t)gr * 8 + h0] = p0;
          a_src[(size_t)gr * 8 + h0 + 1] = p1;
          a_dst[(size_t)gr * 8 + h0] = q0;
          a_dst[(size_t)gr * 8 + h0 + 1] = q1;
        } else {
          a_src[gr] = p0 + p1;
          a_dst[gr] = q0 + q1;
        }
      }
    }
  }
}

// ------- K1: W transposes || degree histogram (+edge rank) -----------------
__global__ __launch_bounds__(256) void prep_hist_kernel(
    const float* __restrict__ W1, const float* __restrict__ W2,
    const int* __restrict__ ei, _Float16* __restrict__ Bt1,
    _Float16* __restrict__ Bt2, int* __restrict__ deg,
    int* __restrict__ edge_rank, int N, int E) {
  int t = threadIdx.x, b = blockIdx.x;
  if (b < 128) {
    int o = b * 256 + t;  // o = n*128 + k
    int nn = o >> 7, kk = o & 127;
    Bt1[o] = (_Float16)W1[kk * 256 + nn];
  } else if (b < 192) {
    int o = (b - 128) * 256 + t;  // o = n*256 + k
    int nn = o >> 8, kk = o & 255;
    Bt2[o] = (_Float16)W2[kk * 64 + nn];
  } else {
    int idx = (b - 192) * 256 + t;
    if (idx < E + N) {
      int d = (idx < E) ? ei[E + idx] : (idx - E);
      edge_rank[idx] = atomicAdd(&deg[d], 1);
    }
  }
}

// ------- K2: fused scan (self-carry) -> rowptr -----------------------------
__global__ __launch_bounds__(256) void scan_kernel(
    const int* __restrict__ deg, int* __restrict__ rowptr, int n) {
  __shared__ int sb[256];
  __shared__ int ws[4];
  int t = threadIdx.x, b = blockIdx.x;
  int pre = 0;
  for (int i = t; i < b * 256; i += 256) pre += deg[i];
#pragma unroll
  for (int o = 32; o; o >>= 1) pre += __shfl_xor(pre, o, 64);
  if ((t & 63) == 0) ws[t >> 6] = pre;
  __syncthreads();
  int carry = ws[0] + ws[1] + ws[2] + ws[3];
  int i = b * 256 + t;
  int v = (i < n) ? deg[i] : 0;
  sb[t] = v;
  __syncthreads();
  int x = v;
  for (int off = 1; off < 256; off <<= 1) {
    int y = (t >= off) ? sb[t - off] : 0;
    __syncthreads();
    x += y;
    sb[t] = x;
    __syncthreads();
  }
  int excl = x - v + carry;
  if (i < n) rowptr[i] = excl;
  if (i == n - 1) rowptr[n] = excl + v;
}

// ------- K3: gemm1 tiles || atomic-free scatter ----------------------------
__global__ __launch_bounds__(256) void gemm1_scatter_kernel(
    const float* __restrict__ x, const _Float16* __restrict__ Bt1,
    _Float16* __restrict__ h1h, const float* __restrict__ att_src1,
    const float* __restrict__ att_dst1, float* __restrict__ a_src1,
    float* __restrict__ a_dst1, int N, int tiles1, const int* __restrict__ ei,
    int E, const int* __restrict__ rowptr, const int* __restrict__ edge_rank,
    int* __restrict__ csr_src) {
  int b = blockIdx.x, t = threadIdx.x;
  if (b < tiles1) {
    gemm_tile<128, 256, true>(x, Bt1, h1h, att_src1, att_dst1, a_src1,
                              a_dst1, N, b >> 2, b & 3, t >> 6, t & 63);
  } else {
    int idx = (b - tiles1) * 256 + t;
    if (idx >= E + N) return;
    int s, d;
    if (idx < E) {
      s = ei[idx];
      d = ei[E + idx];
    } else {
      s = d = idx - E;
    }
    csr_src[rowptr[d] + edge_rank[idx]] = s;
  }
}

// ------- K4: agg1 — wave per dst; single-pass softmax (R8 shape) -----------
// lane l owns channels 4l..4l+3 (head l>>3); 8-deep batched gathers.
__global__ __launch_bounds__(256) void agg1_kernel(
    const int* __restrict__ rowptr, const int* __restrict__ csr_src,
    const float* __restrict__ a_src1, const float* __restrict__ a_dst1,
    const __half* __restrict__ h1h, const float* __restrict__ bias,
    _Float16* __restrict__ h_act, int n) {
  int w = threadIdx.x >> 6, l = threadIdx.x & 63;
  int d = blockIdx.x * 4 + w;
  if (d >= n) return;
  int base = rowptr[d], cnt = rowptr[d + 1] - base;
  const int* sp = csr_src + base;
  int hh = l >> 3;  // head of owned channels
  float adst = a_dst1[(size_t)d * 8 + hh];
  float4 acc = make_float4(0.f, 0.f, 0.f, 0.f);
  float p = 0.f;
  int i = 0;
  for (; i + 8 <= cnt; i += 8) {
    int s[8];
    H4 v[8];
    float xv[8];
#pragma unroll
    for (int j = 0; j < 8; j++) s[j] = sp[i + j];
#pragma unroll
    for (int j = 0; j < 8; j++)
      v[j] = *(const H4*)(h1h + (size_t)s[j] * 256 + 4 * l);
#pragma unroll
    for (int j = 0; j < 8; j++) {
      float e = a_src1[(size_t)s[j] * 8 + hh] + adst;
      e = LEAKY(e);
      xv[j] = __expf(e);
      p += xv[j];
    }
#pragma unroll
    for (int j = 0; j < 8; j++) {
      float2 p0 = __half22float2(v[j].a), p1 = __half22float2(v[j].b);
      acc.x = fmaf(p0.x, xv[j], acc.x);
      acc.y = fmaf(p0.y, xv[j], acc.y);
      acc.z = fmaf(p1.x, xv[j], acc.z);
      acc.w = fmaf(p1.y, xv[j], acc.w);
    }
  }
  for (; i < cnt; i++) {
    int s = sp[i];
    float e = a_src1[(size_t)s * 8 + hh] + adst;
    e = LEAKY(e);
    float a = __expf(e);
    p += a;
    H4 v = *(const H4*)(h1h + (size_t)s * 256 + 4 * l);
    float2 p0 = __half22float2(v.a), p1 = __half22float2(v.b);
    acc.x = fmaf(p0.x, a, acc.x);
    acc.y = fmaf(p0.y, a, acc.y);
    acc.z = fmaf(p1.x, a, acc.z);
    acc.w = fmaf(p1.y, a, acc.w);
  }
  float rinv = 1.f / (p + 1e-16f);
  float4 b = *(const float4*)(bias + 4 * l);
  float ox = fmaf(acc.x, rinv, b.x), oy = fmaf(acc.y, rinv, b.y);
  float oz = fmaf(acc.z, rinv, b.z), ow = fmaf(acc.w, rinv, b.w);
  ox = ox > 0.f ? ox : expm1f(ox);
  oy = oy > 0.f ? oy : expm1f(oy);
  oz = oz > 0.f ? oz : expm1f(oz);
  ow = ow > 0.f ? ow : expm1f(ow);
  H4 hv;
  hv.a = __floats2half2_rn(ox, oy);
  hv.b = __floats2half2_rn(oz, ow);
  *(H4*)(h_act + (size_t)d * 256 + 4 * l) = hv;
}

// ------- K5: gemm2 ---------------------------------------------------------
__global__ __launch_bounds__(256) void gemm2_kernel(
    const _Float16* __restrict__ h_act, const _Float16* __restrict__ Bt2,
    _Float16* __restrict__ h2h, const float* __restrict__ att_src2,
    const float* __restrict__ att_dst2, float* __restrict__ a_src2,
    float* __restrict__ a_dst2, int N) {
  gemm_tile<256, 64, false>(h_act, Bt2, h2h, att_src2, att_dst2, a_src2,
                            a_dst2, N, blockIdx.x, 0, threadIdx.x >> 6,
                            threadIdx.x & 63);
}

// ------- K6: agg2 — wave per dst; single-pass softmax (R8 shape) -----------
__global__ __launch_bounds__(256) void agg2_kernel(
    const int* __restrict__ rowptr, const int* __restrict__ csr_src,
    const float* __restrict__ a_src2, const float* __restrict__ a_dst2,
    const __half* __restrict__ h2h, const float* __restrict__ bias,
    float* __restrict__ out, int n) {
  int w = threadIdx.x >> 6, l = threadIdx.x & 63;
  int d = blockIdx.x * 4 + w;
  if (d >= n) return;
  int base = rowptr[d], cnt = rowptr[d + 1] - base;
  const int* sp = csr_src + base;
  float adst = a_dst2[d];
  int e2 = l >> 5;
  int c2 = (l & 31) * 2;
  float2 acc = make_float2(0.f, 0.f);
  float p = 0.f;
  int i = 0;
  for (; i + 16 <= cnt; i += 16) {
    int s[8];
    __half2 v[8];
    float xv[8];
#pragma unroll
    for (int j = 0; j < 8; j++) s[j] = sp[i + j * 2 + e2];
#pragma unroll
    for (int j = 0; j < 8; j++)
      v[j] = *(const __half2*)(h2h + (size_t)s[j] * 64 + c2);
#pragma unroll
    for (int j = 0; j < 8; j++) {
      float e = a_src2[s[j]] + adst;
      e = LEAKY(e);
      xv[j] = __expf(e);
      p += xv[j];
    }
#pragma unroll
    for (int j = 0; j < 8; j++) {
      float2 f = __half22float2(v[j]);
      acc.x = fmaf(f.x, xv[j], acc.x);
      acc.y = fmaf(f.y, xv[j], acc.y);
    }
  }
  for (; i + e2 < cnt; i += 2) {
    int s = sp[i + e2];
    float e = a_src2[s] + adst;
    e = LEAKY(e);
    float a = __expf(e);
    p += a;
    float2 f = __half22float2(*(const __half2*)(h2h + (size_t)s * 64 + c2));
    acc.x = fmaf(f.x, a, acc.x);
    acc.y = fmaf(f.y, a, acc.y);
  }
  acc.x += __shfl_xor(acc.x, 32, 64);
  acc.y += __shfl_xor(acc.y, 32, 64);
  p += __shfl_xor(p, 32, 64);
  if (l < 32) {
    float rinv = 1.f / (p + 1e-16f);
    float2 b = *(const float2*)(bias + c2);
    *(float2*)(out + (size_t)d * 64 + c2) =
        make_float2(fmaf(acc.x, rinv, b.x), fmaf(acc.y, rinv, b.y));
  }
}

// ---------------------------------------------------------------------------
extern "C" void kernel_launch(void* const* d_in, const int* in_sizes, int n_in,
                              void* d_out, int out_size, void* d_ws, size_t ws_size,
                              hipStream_t stream) {
  const float* x        = (const float*)d_in[0];
  const int*   ei       = (const int*)d_in[1];
  const float* W1       = (const float*)d_in[3];
  const float* att_src1 = (const float*)d_in[4];
  const float* att_dst1 = (const float*)d_in[5];
  const float* bias1    = (const float*)d_in[6];
  const float* W2       = (const float*)d_in[7];
  const float* att_src2 = (const float*)d_in[8];
  const float* att_dst2 = (const float*)d_in[9];
  const float* bias2    = (const float*)d_in[10];
  float* out = (float*)d_out;

  int N = in_sizes[0] / 128;
  int E = in_sizes[1] / 2;
  int Etot = E + N;
  int nb = (N + 255) / 256;

  char* ws = (char*)d_ws;
  size_t off = 0;
  auto carve = [&](size_t bytes) -> void* {
    void* p = ws + off;
    off += (bytes + 255) & ~(size_t)255;
    return p;
  };
  _Float16* Bt1   = (_Float16*)carve((size_t)256 * 128 * 2);
  _Float16* Bt2   = (_Float16*)carve((size_t)64 * 256 * 2);
  _Float16* h1h   = (_Float16*)carve((size_t)N * 256 * 2);  // [N][256]
  _Float16* h2h   = (_Float16*)carve((size_t)N * 64 * 2);   // [N][64]
  _Float16* h_act = (_Float16*)carve((size_t)N * 256 * 2);  // [N][256]
  float* a_src1  = (float*)carve((size_t)N * 8 * 4);        // [N][8]
  float* a_dst1  = (float*)carve((size_t)N * 8 * 4);
  float* a_src2  = (float*)carve((size_t)N * 4);
  float* a_dst2  = (float*)carve((size_t)N * 4);
  int* rowptr    = (int*)carve((size_t)(N + 1) * 4);
  int* deg       = (int*)carve((size_t)N * 4);
  int* edge_rank = (int*)carve((size_t)Etot * 4);
  int* csr_src   = (int*)carve((size_t)Etot * 4);
  (void)ws_size; (void)n_in; (void)out_size;

  hipMemsetAsync(deg, 0, (size_t)N * 4, stream);
  // K1: W transposes || degree histogram (+edge ranks)
  {
    int grid = 192 + (Etot + 255) / 256;
    prep_hist_kernel<<<grid, 256, 0, stream>>>(W1, W2, ei, Bt1, Bt2, deg,
                                               edge_rank, N, E);
  }
  // K2: fused scan -> rowptr
  scan_kernel<<<nb, 256, 0, stream>>>(deg, rowptr, N);
  // K3: gemm1 (MFMA) || atomic-free scatter
  int tiles1 = ((N + 127) / 128) * 4;
  {
    int grid = tiles1 + (Etot + 255) / 256;
    gemm1_scatter_kernel<<<grid, 256, 0, stream>>>(
        x, Bt1, h1h, att_src1, att_dst1, a_src1, a_dst1, N, tiles1, ei, E,
        rowptr, edge_rank, csr_src);
  }
  // K4: agg1 (+bias+ELU, fp16 out)
  agg1_kernel<<<(N + 3) / 4, 256, 0, stream>>>(
      rowptr, csr_src, a_src1, a_dst1, (const __half*)h1h, bias1, h_act, N);
  // K5: gemm2 (MFMA)
  gemm2_kernel<<<(N + 127) / 128, 256, 0, stream>>>(
      h_act, Bt2, h2h, att_src2, att_dst2, a_src2, a_dst2, N);
  // K6: agg2 (+bias)
  agg2_kernel<<<(N + 3) / 4, 256, 0, stream>>>(
      rowptr, csr_src, a_src2, a_dst2, (const __half*)h2h, bias2, out, N);
}